// Round 4
// baseline (110.524 us; speedup 1.0000x reference)
//
#include <hip/hip_runtime.h>
#include <hip/hip_bf16.h>
#include <cstdint>

#define BATCH   32
#define NVARS   16
#define SAMPLES 4096
#define EDIM    128
#define NTOK    1016          // (4096-32)/4
#define PLELEM  4368          // bf16 per plane slot = 8736 B (16B-aligned)

typedef __bf16 bf8_t __attribute__((ext_vector_type(8)));
typedef float  f4_t  __attribute__((ext_vector_type(4)));

// ---------------------------------------------------------------------------
// prep_kernel: W_patch repack ONLY.
// WtF[kb][g(8)][lane(64)][t(8)] = B[kbase(kb)+quad*8+t][g*16+l15]
//   (kbase=(4*dlt+(s&3))*128+(s>>2)*32, kb=s*8+dlt) -> a GEMM wave's
//   B-fragment group is one coalesced 1KB global load straight to VGPRs.
// ---------------------------------------------------------------------------
__global__ __launch_bounds__(256) void prep_kernel(
    const float* __restrict__ Wp, __hip_bfloat16* __restrict__ WtF)
{
  __shared__ float ls[32][132];
  int tid = threadIdx.x;
  int kb  = blockIdx.x;
  int s = kb >> 3, dlt = kb & 7;
  int kbase = (4 * dlt + (s & 3)) * 128 + (s >> 2) * 32;
#pragma unroll
  for (int r = 0; r < 16; ++r) {
    int idx = tid + r * 256;
    ls[idx >> 7][idx & 127] =
        Wp[(size_t)(kbase + (idx >> 7)) * EDIM + (idx & 127)];
  }
  __syncthreads();
  int g = tid >> 5, l5 = tid & 31;
#pragma unroll
  for (int h = 0; h < 2; ++h) {
    int lane = l5 + h * 32;
    int quad = lane >> 4, l15 = lane & 15;
    int n = g * 16 + l15;
    union { unsigned short u[8]; uint4 v; } pk;
#pragma unroll
    for (int t = 0; t < 8; ++t) {
      __hip_bfloat16 hh = __float2bfloat16(ls[quad * 8 + t][n]);
      pk.u[t] = *(unsigned short*)&hh;
    }
    *(uint4*)(WtF + (size_t)kb * 4096 + g * 512 + lane * 8) = pk.v;
  }
}

// ---------------------------------------------------------------------------
// R4: phase-split fusion (R3 structure) + K-split-4 GEMM.
// R3 post-mortem: GEMM phase was B-L2-bound (2 MB/CU, with wq0/wq2 wave
// pairs reading IDENTICAL 256KB B streams) + af read->use latency.
// R4: 8 waves = 4 K-quarters (g2) x 2 N-halves (nh); wave tile M=128xN=64,
// acc 8x4 -> each B fragment feeds 8 MFMA (was 4): B traffic 2MB->1MB/CU,
// zero duplicate streams.  af fragments double-buffered (afA/afB) so the
// 8 ds_read_b128 of step d+1 issue before step d's 32-MFMA cluster.
// kb identity: wave g2 handles kb = g2*32 + ss*8 + d; plane e=g2, p=ss
// (s = kb>>3 = g2*4+ss -> s>>2 = g2, s&3 = ss)  -> bit-identical K-order.
// Epilogue: 4-partial reduction via LDS at stride-20 floats (80B rows:
// lanes 0-7 cover all 32 banks, 8-15 alias 2-way = free) with b128
// vector ops; 2 mi per round, 4 rounds, 8 barriers.
// ---------------------------------------------------------------------------
__global__ __launch_bounds__(512, 2) void fused_kernel(
    const float* __restrict__ x,
    const float* __restrict__ Ws,
    const float* __restrict__ bs,
    const __hip_bfloat16* __restrict__ WtF,
    const float* __restrict__ bp,
    float* __restrict__ out)
{
  __shared__ __align__(16) __hip_bfloat16 Apan[16 * PLELEM];  // 139,776 B
  __shared__ __align__(16) float xTp[2][136][16];             //  17,408 B

  int tid  = threadIdx.x;
  int lane = tid & 63;
  int wv   = tid >> 6;               // 0..7
  int g2   = wv >> 1;                // K-quarter 0..3
  int nh   = wv & 1;                 // N-half
  int b    = blockIdx.x >> 3;
  int t0   = (blockIdx.x & 7) << 7;
  int quad = lane >> 4;
  int l15  = lane & 15;

  const __hip_bfloat16* bg = WtF + (size_t)(nh * 4) * 512 + lane * 8;

  // ---------------- encode setup: fixed dim-quad per thread --------------
  int q4 = tid & 31;                 // dims 4*q4 .. 4*q4+3
  int eq = q4 >> 3;                  // e-block 0..3
  int cq = (q4 >> 1) & 3;            // 16B chunk within row
  int hq = q4 & 1;                   // 8B half within chunk
  int r0 = tid >> 5;                 // 0..15 (row base, +16j)

  float w[NVARS][4];
  float bz[4];
  {
    int d0 = q4 * 4;
#pragma unroll
    for (int v = 0; v < NVARS; ++v)
      *(float4*)&w[v][0] = *(const float4*)(Ws + v * EDIM + d0);
    *(float4*)&bz[0] = *(const float4*)(bs + d0);
  }

  // ---------------- x -> regs: (row, var), float4 = 4 phases -------------
  int vv = tid & 15, rr = tid >> 4;  // rr 0..31
  float4 xreg[5];
  {
    const float* xb = x + ((size_t)b * NVARS + vv) * SAMPLES;
#pragma unroll
    for (int j = 0; j < 4; ++j) {
      int s4 = (t0 + rr + 32 * j) * 4;           // max 4092: in bounds
      xreg[j] = *(const float4*)(xb + s4);
    }
    if (tid < 128) {                             // rows 128..135 (rr<8)
      int s4 = (t0 + 128 + rr) * 4;
      if (s4 > SAMPLES - 4) s4 = SAMPLES - 4;    // clamp (masked tokens only)
      xreg[4] = *(const float4*)(xb + s4);
    }
  }

  // ---------------- phase staging + encode -------------------------------
  auto stageX = [&](int p, int buf) {
#pragma unroll
    for (int j = 0; j < 4; ++j) {
      float c = (p == 0) ? xreg[j].x : (p == 1) ? xreg[j].y
              : (p == 2) ? xreg[j].z : xreg[j].w;
      xTp[buf][rr + 32 * j][vv] = c;
    }
    if (tid < 128) {
      float c = (p == 0) ? xreg[4].x : (p == 1) ? xreg[4].y
              : (p == 2) ? xreg[4].z : xreg[4].w;
      xTp[buf][128 + rr][vv] = c;
    }
  };

  auto encTask = [&](int p, int buf, int r) {
    const float* xr = &xTp[buf][r][0];
    float xv[NVARS];
    *(float4*)&xv[0]  = *(const float4*)(xr + 0);
    *(float4*)&xv[4]  = *(const float4*)(xr + 4);
    *(float4*)&xv[8]  = *(const float4*)(xr + 8);
    *(float4*)&xv[12] = *(const float4*)(xr + 12);
    float a0 = bz[0], a1 = bz[1], a2 = bz[2], a3 = bz[3];
#pragma unroll
    for (int v = 0; v < NVARS; ++v) {
      a0 += xv[v] * w[v][0]; a1 += xv[v] * w[v][1];
      a2 += xv[v] * w[v][2]; a3 += xv[v] * w[v][3];
    }
    union { unsigned short us[4]; uint2 q; } pk;
    pk.us[0] = (unsigned short)(__float_as_uint(floorf(a0)) >> 16);
    pk.us[1] = (unsigned short)(__float_as_uint(floorf(a1)) >> 16);
    pk.us[2] = (unsigned short)(__float_as_uint(floorf(a2)) >> 16);
    pk.us[3] = (unsigned short)(__float_as_uint(floorf(a3)) >> 16);
    int phys = (cq + (r >> 1)) & 3;              // t0 contributes 0 mod 4
    char* plbase = (char*)&Apan[(eq * 4 + p) * PLELEM];
    *(uint2*)(plbase + r * 64 + phys * 16 + hq * 8) = pk.q;
  };

  stageX(0, 0);
  __syncthreads();
#pragma unroll
  for (int p = 0; p < 4; ++p) {
    if (p < 3) stageX(p + 1, (p + 1) & 1);
    int buf = p & 1;
#pragma unroll
    for (int j = 0; j < 8; ++j) encTask(p, buf, r0 + 16 * j);
    if (tid < 256) encTask(p, buf, 128 + (tid >> 5));
    __syncthreads();
  }
  // panel fully resident; no further A traffic, no barriers until epilogue

  // ---------------- GEMM main loop (barrier-free, K-split-4) -------------
  f4_t acc[8][4];
  f4_t zero = {0.f, 0.f, 0.f, 0.f};
#pragma unroll
  for (int i = 0; i < 8; ++i)
#pragma unroll
    for (int j = 0; j < 4; ++j) acc[i][j] = zero;

  auto loadB = [&](int kb, uint4* d) {
#pragma unroll
    for (int j = 0; j < 4; ++j)
      d[j] = *(const uint4*)(bg + (size_t)kb * 4096 + j * 512);
  };

  auto loadAF = [&](bf8_t* af, const bf8_t* pA, int dlt) {
    int swz = (quad + ((t0 + dlt + l15) >> 1)) & 3;
#pragma unroll
    for (int i = 0; i < 8; ++i)
      af[i] = pA[(dlt + i * 16 + l15) * 4 + swz];
  };

  auto mstep = [&](const bf8_t* af, const uint4* bq_) {
    __builtin_amdgcn_s_setprio(1);
#pragma unroll
    for (int mi = 0; mi < 8; ++mi)
#pragma unroll
      for (int ni = 0; ni < 4; ++ni)
        acc[mi][ni] = __builtin_amdgcn_mfma_f32_16x16x32_bf16(
            af[mi], __builtin_bit_cast(bf8_t, bq_[ni]), acc[mi][ni], 0, 0, 0);
    __builtin_amdgcn_s_setprio(0);
  };

  bf8_t afA[8], afB[8];
  uint4 bq[2][4];
  loadB(g2 * 32 + 0, bq[0]);
  loadB(g2 * 32 + 1, bq[1]);
  loadAF(afA, (const bf8_t*)&Apan[(g2 * 4) * PLELEM], 0);

  for (int ss = 0; ss < 4; ++ss) {
    const bf8_t* pA  = (const bf8_t*)&Apan[(g2 * 4 + ss) * PLELEM];
    const bf8_t* pAn = (const bf8_t*)&Apan[(g2 * 4 + ss + 1) * PLELEM];
#pragma unroll
    for (int d = 0; d < 8; ++d) {
      int kl = ss * 8 + d;
      if ((d & 1) == 0) {
        if (d < 7) loadAF(afB, pA, d + 1);
        mstep(afA, bq[0]);
      } else {
        if (d < 7)      loadAF(afA, pA, d + 1);
        else if (ss < 3) loadAF(afA, pAn, 0);
        mstep(afB, bq[1]);
      }
      if (kl < 30) loadB(g2 * 32 + kl + 2, bq[d & 1]);
    }
  }

  // ---- 4-partial K reduction (g2 1..3 -> g2 0) + fused epilogue ----
  // rb2: [768][20] floats over Apan (61,440 B).  Pitch 20 f (80 B): b128
  // writes/reads 2-way bank alias = free.  2 mi per round, 4 rounds.
  float* rb2 = (float*)&Apan[0];
  float bias[4];
#pragma unroll
  for (int ni = 0; ni < 4; ++ni) bias[ni] = bp[(nh << 6) + ni * 16 + l15];

#pragma unroll
  for (int rd = 0; rd < 4; ++rd) {
    __syncthreads();
    if (g2 > 0) {
      int slot = ((g2 - 1) * 2 + nh) * 64 + lane;
#pragma unroll
      for (int mh = 0; mh < 2; ++mh) {
        int mi = rd * 2 + mh;
#pragma unroll
        for (int ni = 0; ni < 4; ++ni)
          *(f4_t*)&rb2[(size_t)(slot + mh * 384) * 20 + ni * 4] = acc[mi][ni];
      }
    }
    __syncthreads();
    if (g2 == 0) {
#pragma unroll
      for (int mh = 0; mh < 2; ++mh) {
        int mi = rd * 2 + mh;
        f4_t s0 = acc[mi][0], s1 = acc[mi][1];
        f4_t s2 = acc[mi][2], s3 = acc[mi][3];
#pragma unroll
        for (int q = 1; q < 4; ++q) {
          int sl = ((q - 1) * 2 + nh) * 64 + lane + mh * 384;
          s0 += *(const f4_t*)&rb2[(size_t)sl * 20 + 0];
          s1 += *(const f4_t*)&rb2[(size_t)sl * 20 + 4];
          s2 += *(const f4_t*)&rb2[(size_t)sl * 20 + 8];
          s3 += *(const f4_t*)&rb2[(size_t)sl * 20 + 12];
        }
        f4_t sv[4] = {s0, s1, s2, s3};
#pragma unroll
        for (int ni = 0; ni < 4; ++ni)
#pragma unroll
          for (int r = 0; r < 4; ++r) {
            int t = t0 + mi * 16 + quad * 4 + r;
            if (t < NTOK) {
              int n = (nh << 6) + ni * 16 + l15;
              out[((size_t)b * NTOK + t) * EDIM + n] =
                  floorf(sv[ni][r] + bias[ni]);
            }
          }
      }
    }
  }
}

// ---------------------------------------------------------------------------
extern "C" void kernel_launch(void* const* d_in, const int* in_sizes, int n_in,
                              void* d_out, int out_size, void* d_ws, size_t ws_size,
                              hipStream_t stream) {
  const float* x  = (const float*)d_in[0];
  const float* Ws = (const float*)d_in[1];
  const float* bs = (const float*)d_in[2];
  const float* Wp = (const float*)d_in[3];
  const float* bp = (const float*)d_in[4];
  float* out = (float*)d_out;

  __hip_bfloat16* WtF = (__hip_bfloat16*)d_ws;   // 1 MB fragment-major B

  prep_kernel<<<128, 256, 0, stream>>>(Wp, WtF);
  fused_kernel<<<BATCH * 8, 512, 0, stream>>>(x, Ws, bs, WtF, bp, out);
}

// Round 5
// 110.122 us; speedup vs baseline: 1.0037x; 1.0037x over previous
//
#include <hip/hip_runtime.h>
#include <hip/hip_bf16.h>
#include <cstdint>

#define BATCH   32
#define NVARS   16
#define SAMPLES 4096
#define EDIM    128
#define NTOK    1016          // (4096-32)/4
#define PLELEM  4368          // bf16 per plane slot = 8736 B (16B-aligned)

typedef __bf16 bf8_t __attribute__((ext_vector_type(8)));
typedef float  f4_t  __attribute__((ext_vector_type(4)));

// ---------------------------------------------------------------------------
// prep_kernel: W_patch repack ONLY.
// WtF[kb][g(8)][lane(64)][t(8)] = B[kbase(kb)+quad*8+t][g*16+l15]
//   (kbase=(4*dlt+(s&3))*128+(s>>2)*32, kb=s*8+dlt) -> a GEMM wave's
//   B-fragment group is one coalesced 1KB global load straight to VGPRs.
// ---------------------------------------------------------------------------
__global__ __launch_bounds__(256) void prep_kernel(
    const float* __restrict__ Wp, __hip_bfloat16* __restrict__ WtF)
{
  __shared__ float ls[32][132];
  int tid = threadIdx.x;
  int kb  = blockIdx.x;
  int s = kb >> 3, dlt = kb & 7;
  int kbase = (4 * dlt + (s & 3)) * 128 + (s >> 2) * 32;
#pragma unroll
  for (int r = 0; r < 16; ++r) {
    int idx = tid + r * 256;
    ls[idx >> 7][idx & 127] =
        Wp[(size_t)(kbase + (idx >> 7)) * EDIM + (idx & 127)];
  }
  __syncthreads();
  int g = tid >> 5, l5 = tid & 31;
#pragma unroll
  for (int h = 0; h < 2; ++h) {
    int lane = l5 + h * 32;
    int quad = lane >> 4, l15 = lane & 15;
    int n = g * 16 + l15;
    union { unsigned short u[8]; uint4 v; } pk;
#pragma unroll
    for (int t = 0; t < 8; ++t) {
      __hip_bfloat16 hh = __float2bfloat16(ls[quad * 8 + t][n]);
      pk.u[t] = *(unsigned short*)&hh;
    }
    *(uint4*)(WtF + (size_t)kb * 4096 + g * 512 + lane * 8) = pk.v;
  }
}

// ---------------------------------------------------------------------------
// R5 = R4 with __launch_bounds__(512, 1).
// R4 post-mortem: (512,2) capped VGPR at 128 while the K-split-4 live set
// needs ~240 -> scratch spills (FETCH +4.1 MB, WRITE +8.2 MB per dispatch,
// fused 45.3->49.3 us).  The ",2" bought nothing: LDS=157 KB already
// forces 1 block/CU.  (512,1) restores the 256-VGPR budget; everything
// else is bit-identical to R4.
//
// Structure recap: phase-split fusion (encode once into LDS-resident
// 16-plane A-panel, barrier-free GEMM) + K-split-4: 8 waves = 4 K-quarters
// (g2) x 2 N-halves (nh); wave tile M=128xN=64, acc 8x4 -> each B fragment
// feeds 8 MFMA: B-L2 traffic 1 MB/CU, no duplicate streams.  af fragments
// double-buffered.  kb identity: wave g2 handles kb = g2*32 + ss*8 + d;
// plane e=g2, p=ss -> bit-identical K-order vs R0 reference kernel.
// ---------------------------------------------------------------------------
__global__ __launch_bounds__(512, 1) void fused_kernel(
    const float* __restrict__ x,
    const float* __restrict__ Ws,
    const float* __restrict__ bs,
    const __hip_bfloat16* __restrict__ WtF,
    const float* __restrict__ bp,
    float* __restrict__ out)
{
  __shared__ __align__(16) __hip_bfloat16 Apan[16 * PLELEM];  // 139,776 B
  __shared__ __align__(16) float xTp[2][136][16];             //  17,408 B

  int tid  = threadIdx.x;
  int lane = tid & 63;
  int wv   = tid >> 6;               // 0..7
  int g2   = wv >> 1;                // K-quarter 0..3
  int nh   = wv & 1;                 // N-half
  int b    = blockIdx.x >> 3;
  int t0   = (blockIdx.x & 7) << 7;
  int quad = lane >> 4;
  int l15  = lane & 15;

  const __hip_bfloat16* bg = WtF + (size_t)(nh * 4) * 512 + lane * 8;

  // ---------------- encode setup: fixed dim-quad per thread --------------
  int q4 = tid & 31;                 // dims 4*q4 .. 4*q4+3
  int eq = q4 >> 3;                  // e-block 0..3
  int cq = (q4 >> 1) & 3;            // 16B chunk within row
  int hq = q4 & 1;                   // 8B half within chunk
  int r0 = tid >> 5;                 // 0..15 (row base, +16j)

  float w[NVARS][4];
  float bz[4];
  {
    int d0 = q4 * 4;
#pragma unroll
    for (int v = 0; v < NVARS; ++v)
      *(float4*)&w[v][0] = *(const float4*)(Ws + v * EDIM + d0);
    *(float4*)&bz[0] = *(const float4*)(bs + d0);
  }

  // ---------------- x -> regs: (row, var), float4 = 4 phases -------------
  int vv = tid & 15, rr = tid >> 4;  // rr 0..31
  float4 xreg[5];
  {
    const float* xb = x + ((size_t)b * NVARS + vv) * SAMPLES;
#pragma unroll
    for (int j = 0; j < 4; ++j) {
      int s4 = (t0 + rr + 32 * j) * 4;           // max 4092: in bounds
      xreg[j] = *(const float4*)(xb + s4);
    }
    if (tid < 128) {                             // rows 128..135 (rr<8)
      int s4 = (t0 + 128 + rr) * 4;
      if (s4 > SAMPLES - 4) s4 = SAMPLES - 4;    // clamp (masked tokens only)
      xreg[4] = *(const float4*)(xb + s4);
    }
  }

  // ---------------- phase staging + encode -------------------------------
  auto stageX = [&](int p, int buf) {
#pragma unroll
    for (int j = 0; j < 4; ++j) {
      float c = (p == 0) ? xreg[j].x : (p == 1) ? xreg[j].y
              : (p == 2) ? xreg[j].z : xreg[j].w;
      xTp[buf][rr + 32 * j][vv] = c;
    }
    if (tid < 128) {
      float c = (p == 0) ? xreg[4].x : (p == 1) ? xreg[4].y
              : (p == 2) ? xreg[4].z : xreg[4].w;
      xTp[buf][128 + rr][vv] = c;
    }
  };

  auto encTask = [&](int p, int buf, int r) {
    const float* xr = &xTp[buf][r][0];
    float xv[NVARS];
    *(float4*)&xv[0]  = *(const float4*)(xr + 0);
    *(float4*)&xv[4]  = *(const float4*)(xr + 4);
    *(float4*)&xv[8]  = *(const float4*)(xr + 8);
    *(float4*)&xv[12] = *(const float4*)(xr + 12);
    float a0 = bz[0], a1 = bz[1], a2 = bz[2], a3 = bz[3];
#pragma unroll
    for (int v = 0; v < NVARS; ++v) {
      a0 += xv[v] * w[v][0]; a1 += xv[v] * w[v][1];
      a2 += xv[v] * w[v][2]; a3 += xv[v] * w[v][3];
    }
    union { unsigned short us[4]; uint2 q; } pk;
    pk.us[0] = (unsigned short)(__float_as_uint(floorf(a0)) >> 16);
    pk.us[1] = (unsigned short)(__float_as_uint(floorf(a1)) >> 16);
    pk.us[2] = (unsigned short)(__float_as_uint(floorf(a2)) >> 16);
    pk.us[3] = (unsigned short)(__float_as_uint(floorf(a3)) >> 16);
    int phys = (cq + (r >> 1)) & 3;              // t0 contributes 0 mod 4
    char* plbase = (char*)&Apan[(eq * 4 + p) * PLELEM];
    *(uint2*)(plbase + r * 64 + phys * 16 + hq * 8) = pk.q;
  };

  stageX(0, 0);
  __syncthreads();
#pragma unroll
  for (int p = 0; p < 4; ++p) {
    if (p < 3) stageX(p + 1, (p + 1) & 1);
    int buf = p & 1;
#pragma unroll
    for (int j = 0; j < 8; ++j) encTask(p, buf, r0 + 16 * j);
    if (tid < 256) encTask(p, buf, 128 + (tid >> 5));
    __syncthreads();
  }
  // panel fully resident; no further A traffic, no barriers until epilogue

  // ---------------- GEMM main loop (barrier-free, K-split-4) -------------
  f4_t acc[8][4];
  f4_t zero = {0.f, 0.f, 0.f, 0.f};
#pragma unroll
  for (int i = 0; i < 8; ++i)
#pragma unroll
    for (int j = 0; j < 4; ++j) acc[i][j] = zero;

  auto loadB = [&](int kb, uint4* d) {
#pragma unroll
    for (int j = 0; j < 4; ++j)
      d[j] = *(const uint4*)(bg + (size_t)kb * 4096 + j * 512);
  };

  auto loadAF = [&](bf8_t* af, const bf8_t* pA, int dlt) {
    int swz = (quad + ((t0 + dlt + l15) >> 1)) & 3;
#pragma unroll
    for (int i = 0; i < 8; ++i)
      af[i] = pA[(dlt + i * 16 + l15) * 4 + swz];
  };

  auto mstep = [&](const bf8_t* af, const uint4* bq_) {
    __builtin_amdgcn_s_setprio(1);
#pragma unroll
    for (int mi = 0; mi < 8; ++mi)
#pragma unroll
      for (int ni = 0; ni < 4; ++ni)
        acc[mi][ni] = __builtin_amdgcn_mfma_f32_16x16x32_bf16(
            af[mi], __builtin_bit_cast(bf8_t, bq_[ni]), acc[mi][ni], 0, 0, 0);
    __builtin_amdgcn_s_setprio(0);
  };

  bf8_t afA[8], afB[8];
  uint4 bq[2][4];
  loadB(g2 * 32 + 0, bq[0]);
  loadB(g2 * 32 + 1, bq[1]);
  loadAF(afA, (const bf8_t*)&Apan[(g2 * 4) * PLELEM], 0);

  for (int ss = 0; ss < 4; ++ss) {
    const bf8_t* pA  = (const bf8_t*)&Apan[(g2 * 4 + ss) * PLELEM];
    const bf8_t* pAn = (const bf8_t*)&Apan[(g2 * 4 + ss + 1) * PLELEM];
#pragma unroll
    for (int d = 0; d < 8; ++d) {
      int kl = ss * 8 + d;
      if ((d & 1) == 0) {
        if (d < 7) loadAF(afB, pA, d + 1);
        mstep(afA, bq[0]);
      } else {
        if (d < 7)      loadAF(afA, pA, d + 1);
        else if (ss < 3) loadAF(afA, pAn, 0);
        mstep(afB, bq[1]);
      }
      if (kl < 30) loadB(g2 * 32 + kl + 2, bq[d & 1]);
    }
  }

  // ---- 4-partial K reduction (g2 1..3 -> g2 0) + fused epilogue ----
  // rb2: [768][20] floats over Apan (61,440 B).  Pitch 20 f (80 B): b128
  // writes/reads 2-way bank alias = free.  2 mi per round, 4 rounds.
  float* rb2 = (float*)&Apan[0];
  float bias[4];
#pragma unroll
  for (int ni = 0; ni < 4; ++ni) bias[ni] = bp[(nh << 6) + ni * 16 + l15];

#pragma unroll
  for (int rd = 0; rd < 4; ++rd) {
    __syncthreads();
    if (g2 > 0) {
      int slot = ((g2 - 1) * 2 + nh) * 64 + lane;
#pragma unroll
      for (int mh = 0; mh < 2; ++mh) {
        int mi = rd * 2 + mh;
#pragma unroll
        for (int ni = 0; ni < 4; ++ni)
          *(f4_t*)&rb2[(size_t)(slot + mh * 384) * 20 + ni * 4] = acc[mi][ni];
      }
    }
    __syncthreads();
    if (g2 == 0) {
#pragma unroll
      for (int mh = 0; mh < 2; ++mh) {
        int mi = rd * 2 + mh;
        f4_t s0 = acc[mi][0], s1 = acc[mi][1];
        f4_t s2 = acc[mi][2], s3 = acc[mi][3];
#pragma unroll
        for (int q = 1; q < 4; ++q) {
          int sl = ((q - 1) * 2 + nh) * 64 + lane + mh * 384;
          s0 += *(const f4_t*)&rb2[(size_t)sl * 20 + 0];
          s1 += *(const f4_t*)&rb2[(size_t)sl * 20 + 4];
          s2 += *(const f4_t*)&rb2[(size_t)sl * 20 + 8];
          s3 += *(const f4_t*)&rb2[(size_t)sl * 20 + 12];
        }
        f4_t sv[4] = {s0, s1, s2, s3};
#pragma unroll
        for (int ni = 0; ni < 4; ++ni)
#pragma unroll
          for (int r = 0; r < 4; ++r) {
            int t = t0 + mi * 16 + quad * 4 + r;
            if (t < NTOK) {
              int n = (nh << 6) + ni * 16 + l15;
              out[((size_t)b * NTOK + t) * EDIM + n] =
                  floorf(sv[ni][r] + bias[ni]);
            }
          }
      }
    }
  }
}

// ---------------------------------------------------------------------------
extern "C" void kernel_launch(void* const* d_in, const int* in_sizes, int n_in,
                              void* d_out, int out_size, void* d_ws, size_t ws_size,
                              hipStream_t stream) {
  const float* x  = (const float*)d_in[0];
  const float* Ws = (const float*)d_in[1];
  const float* bs = (const float*)d_in[2];
  const float* Wp = (const float*)d_in[3];
  const float* bp = (const float*)d_in[4];
  float* out = (float*)d_out;

  __hip_bfloat16* WtF = (__hip_bfloat16*)d_ws;   // 1 MB fragment-major B

  prep_kernel<<<128, 256, 0, stream>>>(Wp, WtF);
  fused_kernel<<<BATCH * 8, 512, 0, stream>>>(x, Ws, bs, WtF, bp, out);
}

// Round 6
// 107.020 us; speedup vs baseline: 1.0327x; 1.0290x over previous
//
#include <hip/hip_runtime.h>
#include <hip/hip_bf16.h>
#include <cstdint>

#define BATCH   32
#define NVARS   16
#define SAMPLES 4096
#define EDIM    128
#define NTOK    1016          // (4096-32)/4
#define PLELEM  4368          // bf16 per plane slot = 8736 B (16B-aligned)

typedef __bf16 bf8_t __attribute__((ext_vector_type(8)));
typedef float  f4_t  __attribute__((ext_vector_type(4)));

// ---------------------------------------------------------------------------
// prep_kernel: W_patch repack ONLY.
// WtF[kb][g(8)][lane(64)][t(8)] = B[kbase(kb)+quad*8+t][g*16+l15]
//   (kbase=(4*dlt+(s&3))*128+(s>>2)*32, kb=s*8+dlt) -> a GEMM wave's
//   B-fragment group is one coalesced 1KB global load straight to VGPRs.
// ---------------------------------------------------------------------------
__global__ __launch_bounds__(256) void prep_kernel(
    const float* __restrict__ Wp, __hip_bfloat16* __restrict__ WtF)
{
  __shared__ float ls[32][132];
  int tid = threadIdx.x;
  int kb  = blockIdx.x;
  int s = kb >> 3, dlt = kb & 7;
  int kbase = (4 * dlt + (s & 3)) * 128 + (s >> 2) * 32;
#pragma unroll
  for (int r = 0; r < 16; ++r) {
    int idx = tid + r * 256;
    ls[idx >> 7][idx & 127] =
        Wp[(size_t)(kbase + (idx >> 7)) * EDIM + (idx & 127)];
  }
  __syncthreads();
  int g = tid >> 5, l5 = tid & 31;
#pragma unroll
  for (int h = 0; h < 2; ++h) {
    int lane = l5 + h * 32;
    int quad = lane >> 4, l15 = lane & 15;
    int n = g * 16 + l15;
    union { unsigned short u[8]; uint4 v; } pk;
#pragma unroll
    for (int t = 0; t < 8; ++t) {
      __hip_bfloat16 hh = __float2bfloat16(ls[quad * 8 + t][n]);
      pk.u[t] = *(unsigned short*)&hh;
    }
    *(uint4*)(WtF + (size_t)kb * 4096 + g * 512 + lane * 8) = pk.v;
  }
}

// ---------------------------------------------------------------------------
// R6: K-split-4 with HALF-FRAGMENT af pipeline (spill fix).
// R4/R5 post-mortem: 8-wave block forces >=2 waves/SIMD -> 256 total
// regs/wave cap; acc[8][4]=128 acc-regs leaves 128 arch.  Full af dbuf
// (64 regs) + bq (32) + misc blew the cap -> scratch spills (FETCH +4.1,
// WRITE +8.2 MB).  (512,1) vs (512,2) compiles IDENTICALLY (clamp).
// R6: af0[4]/af1[4] half-fragment alternation = 32 regs, same read-ahead
// (one 4x ds_read_b128 group in flight ahead of each 16-MFMA cluster).
// Arch live ~90 < 128 -> no spills.  All math / K-order / swizzle /
// epilogue bit-identical to R4.
//
// Structure recap: phase-split fusion (encode once into LDS-resident
// 16-plane A-panel, barrier-free GEMM) + K-split-4: 8 waves = 4 K-quarters
// (g2) x 2 N-halves (nh); wave tile M=128xN=64, acc 8x4 -> each B fragment
// feeds 8 MFMA: B-L2 traffic 1 MB/CU, no duplicate streams.  kb identity:
// wave g2 handles kb = g2*32 + ss*8 + d; plane e=g2, p=ss.
// ---------------------------------------------------------------------------
__global__ __launch_bounds__(512, 2) void fused_kernel(
    const float* __restrict__ x,
    const float* __restrict__ Ws,
    const float* __restrict__ bs,
    const __hip_bfloat16* __restrict__ WtF,
    const float* __restrict__ bp,
    float* __restrict__ out)
{
  __shared__ __align__(16) __hip_bfloat16 Apan[16 * PLELEM];  // 139,776 B
  __shared__ __align__(16) float xTp[2][136][16];             //  17,408 B

  int tid  = threadIdx.x;
  int lane = tid & 63;
  int wv   = tid >> 6;               // 0..7
  int g2   = wv >> 1;                // K-quarter 0..3
  int nh   = wv & 1;                 // N-half
  int b    = blockIdx.x >> 3;
  int t0   = (blockIdx.x & 7) << 7;
  int quad = lane >> 4;
  int l15  = lane & 15;

  const __hip_bfloat16* bg = WtF + (size_t)(nh * 4) * 512 + lane * 8;

  // ---------------- encode setup: fixed dim-quad per thread --------------
  int q4 = tid & 31;                 // dims 4*q4 .. 4*q4+3
  int eq = q4 >> 3;                  // e-block 0..3
  int cq = (q4 >> 1) & 3;            // 16B chunk within row
  int hq = q4 & 1;                   // 8B half within chunk
  int r0 = tid >> 5;                 // 0..15 (row base, +16j)

  float w[NVARS][4];
  float bz[4];
  {
    int d0 = q4 * 4;
#pragma unroll
    for (int v = 0; v < NVARS; ++v)
      *(float4*)&w[v][0] = *(const float4*)(Ws + v * EDIM + d0);
    *(float4*)&bz[0] = *(const float4*)(bs + d0);
  }

  // ---------------- x -> regs: (row, var), float4 = 4 phases -------------
  int vv = tid & 15, rr = tid >> 4;  // rr 0..31
  float4 xreg[5];
  {
    const float* xb = x + ((size_t)b * NVARS + vv) * SAMPLES;
#pragma unroll
    for (int j = 0; j < 4; ++j) {
      int s4 = (t0 + rr + 32 * j) * 4;           // max 4092: in bounds
      xreg[j] = *(const float4*)(xb + s4);
    }
    if (tid < 128) {                             // rows 128..135 (rr<8)
      int s4 = (t0 + 128 + rr) * 4;
      if (s4 > SAMPLES - 4) s4 = SAMPLES - 4;    // clamp (masked tokens only)
      xreg[4] = *(const float4*)(xb + s4);
    }
  }

  // ---------------- phase staging + encode -------------------------------
  auto stageX = [&](int p, int buf) {
#pragma unroll
    for (int j = 0; j < 4; ++j) {
      float c = (p == 0) ? xreg[j].x : (p == 1) ? xreg[j].y
              : (p == 2) ? xreg[j].z : xreg[j].w;
      xTp[buf][rr + 32 * j][vv] = c;
    }
    if (tid < 128) {
      float c = (p == 0) ? xreg[4].x : (p == 1) ? xreg[4].y
              : (p == 2) ? xreg[4].z : xreg[4].w;
      xTp[buf][128 + rr][vv] = c;
    }
  };

  auto encTask = [&](int p, int buf, int r) {
    const float* xr = &xTp[buf][r][0];
    float xv[NVARS];
    *(float4*)&xv[0]  = *(const float4*)(xr + 0);
    *(float4*)&xv[4]  = *(const float4*)(xr + 4);
    *(float4*)&xv[8]  = *(const float4*)(xr + 8);
    *(float4*)&xv[12] = *(const float4*)(xr + 12);
    float a0 = bz[0], a1 = bz[1], a2 = bz[2], a3 = bz[3];
#pragma unroll
    for (int v = 0; v < NVARS; ++v) {
      a0 += xv[v] * w[v][0]; a1 += xv[v] * w[v][1];
      a2 += xv[v] * w[v][2]; a3 += xv[v] * w[v][3];
    }
    union { unsigned short us[4]; uint2 q; } pk;
    pk.us[0] = (unsigned short)(__float_as_uint(floorf(a0)) >> 16);
    pk.us[1] = (unsigned short)(__float_as_uint(floorf(a1)) >> 16);
    pk.us[2] = (unsigned short)(__float_as_uint(floorf(a2)) >> 16);
    pk.us[3] = (unsigned short)(__float_as_uint(floorf(a3)) >> 16);
    int phys = (cq + (r >> 1)) & 3;              // t0 contributes 0 mod 4
    char* plbase = (char*)&Apan[(eq * 4 + p) * PLELEM];
    *(uint2*)(plbase + r * 64 + phys * 16 + hq * 8) = pk.q;
  };

  stageX(0, 0);
  __syncthreads();
#pragma unroll
  for (int p = 0; p < 4; ++p) {
    if (p < 3) stageX(p + 1, (p + 1) & 1);
    int buf = p & 1;
#pragma unroll
    for (int j = 0; j < 8; ++j) encTask(p, buf, r0 + 16 * j);
    if (tid < 256) encTask(p, buf, 128 + (tid >> 5));
    __syncthreads();
  }
  // panel fully resident; no further A traffic, no barriers until epilogue

  // ---------------- GEMM main loop (barrier-free, K-split-4) -------------
  f4_t acc[8][4];
  f4_t zero = {0.f, 0.f, 0.f, 0.f};
#pragma unroll
  for (int i = 0; i < 8; ++i)
#pragma unroll
    for (int j = 0; j < 4; ++j) acc[i][j] = zero;

  auto loadB = [&](int kb, uint4* d) {
#pragma unroll
    for (int j = 0; j < 4; ++j)
      d[j] = *(const uint4*)(bg + (size_t)kb * 4096 + j * 512);
  };

  // half-fragment loads: h=0 -> rows dlt+{0,16,32,48}+l15,
  //                      h=1 -> rows dlt+{64,80,96,112}+l15.
  // swz uses only (t0+dlt+l15): the i*16 row term is 0 mod 4 after >>1.
  auto loadAF0 = [&](bf8_t* af, const bf8_t* pA, int dlt) {
    int swz = (quad + ((t0 + dlt + l15) >> 1)) & 3;
#pragma unroll
    for (int i = 0; i < 4; ++i)
      af[i] = pA[(dlt + i * 16 + l15) * 4 + swz];
  };
  auto loadAF1 = [&](bf8_t* af, const bf8_t* pA, int dlt) {
    int swz = (quad + ((t0 + dlt + l15) >> 1)) & 3;
#pragma unroll
    for (int i = 0; i < 4; ++i)
      af[i] = pA[(dlt + (i + 4) * 16 + l15) * 4 + swz];
  };

  auto mstepH = [&](const bf8_t* af, const uint4* bq_, int mibase) {
    __builtin_amdgcn_s_setprio(1);
#pragma unroll
    for (int mi = 0; mi < 4; ++mi)
#pragma unroll
      for (int ni = 0; ni < 4; ++ni)
        acc[mibase + mi][ni] = __builtin_amdgcn_mfma_f32_16x16x32_bf16(
            af[mi], __builtin_bit_cast(bf8_t, bq_[ni]),
            acc[mibase + mi][ni], 0, 0, 0);
    __builtin_amdgcn_s_setprio(0);
  };

  bf8_t af0[4], af1[4];
  uint4 bq[2][4];
  loadB(g2 * 32 + 0, bq[0]);
  loadB(g2 * 32 + 1, bq[1]);
  loadAF0(af0, (const bf8_t*)&Apan[(g2 * 4) * PLELEM], 0);

  for (int ss = 0; ss < 4; ++ss) {
    const bf8_t* pA  = (const bf8_t*)&Apan[(g2 * 4 + ss) * PLELEM];
    const bf8_t* pAn = (const bf8_t*)&Apan[(g2 * 4 + ss + 1) * PLELEM];
#pragma unroll
    for (int d = 0; d < 8; ++d) {
      int kl = ss * 8 + d;
      loadAF1(af1, pA, d);                 // half 1 of step d
      mstepH(af0, bq[d & 1], 0);           // compute half 0
      if (d < 7)       loadAF0(af0, pA, d + 1);     // read-ahead half 0
      else if (ss < 3) loadAF0(af0, pAn, 0);
      mstepH(af1, bq[d & 1], 4);           // compute half 1
      if (kl < 30) loadB(g2 * 32 + kl + 2, bq[d & 1]);
    }
  }

  // ---- 4-partial K reduction (g2 1..3 -> g2 0) + fused epilogue ----
  // rb2: [768][20] floats over Apan (61,440 B).  Pitch 20 f (80 B): b128
  // writes/reads 2-way bank alias = free.  2 mi per round, 4 rounds.
  float* rb2 = (float*)&Apan[0];
  float bias[4];
#pragma unroll
  for (int ni = 0; ni < 4; ++ni) bias[ni] = bp[(nh << 6) + ni * 16 + l15];

#pragma unroll
  for (int rd = 0; rd < 4; ++rd) {
    __syncthreads();
    if (g2 > 0) {
      int slot = ((g2 - 1) * 2 + nh) * 64 + lane;
#pragma unroll
      for (int mh = 0; mh < 2; ++mh) {
        int mi = rd * 2 + mh;
#pragma unroll
        for (int ni = 0; ni < 4; ++ni)
          *(f4_t*)&rb2[(size_t)(slot + mh * 384) * 20 + ni * 4] = acc[mi][ni];
      }
    }
    __syncthreads();
    if (g2 == 0) {
#pragma unroll
      for (int mh = 0; mh < 2; ++mh) {
        int mi = rd * 2 + mh;
        f4_t s0 = acc[mi][0], s1 = acc[mi][1];
        f4_t s2 = acc[mi][2], s3 = acc[mi][3];
#pragma unroll
        for (int q = 1; q < 4; ++q) {
          int sl = ((q - 1) * 2 + nh) * 64 + lane + mh * 384;
          s0 += *(const f4_t*)&rb2[(size_t)sl * 20 + 0];
          s1 += *(const f4_t*)&rb2[(size_t)sl * 20 + 4];
          s2 += *(const f4_t*)&rb2[(size_t)sl * 20 + 8];
          s3 += *(const f4_t*)&rb2[(size_t)sl * 20 + 12];
        }
        f4_t sv[4] = {s0, s1, s2, s3};
#pragma unroll
        for (int ni = 0; ni < 4; ++ni)
#pragma unroll
          for (int r = 0; r < 4; ++r) {
            int t = t0 + mi * 16 + quad * 4 + r;
            if (t < NTOK) {
              int n = (nh << 6) + ni * 16 + l15;
              out[((size_t)b * NTOK + t) * EDIM + n] =
                  floorf(sv[ni][r] + bias[ni]);
            }
          }
      }
    }
  }
}

// ---------------------------------------------------------------------------
extern "C" void kernel_launch(void* const* d_in, const int* in_sizes, int n_in,
                              void* d_out, int out_size, void* d_ws, size_t ws_size,
                              hipStream_t stream) {
  const float* x  = (const float*)d_in[0];
  const float* Ws = (const float*)d_in[1];
  const float* bs = (const float*)d_in[2];
  const float* Wp = (const float*)d_in[3];
  const float* bp = (const float*)d_in[4];
  float* out = (float*)d_out;

  __hip_bfloat16* WtF = (__hip_bfloat16*)d_ws;   // 1 MB fragment-major B

  prep_kernel<<<128, 256, 0, stream>>>(Wp, WtF);
  fused_kernel<<<BATCH * 8, 512, 0, stream>>>(x, Ws, bs, WtF, bp, out);
}